// Round 3
// baseline (398.750 us; speedup 1.0000x reference)
//
#include <hip/hip_runtime.h>
#include <math.h>

// Problem constants
#define EMBED   2048
#define NHEADS  16
#define HD      128
#define S_TOT   4096
#define BATCH   64

typedef __attribute__((ext_vector_type(8))) short short8v;
typedef __attribute__((ext_vector_type(4))) short short4v;
typedef __attribute__((ext_vector_type(2))) short short2v;
typedef __attribute__((ext_vector_type(4))) float floatx4;

// fp32 -> bf16, round-to-nearest-even
__device__ __forceinline__ unsigned short f2bf(float f) {
    unsigned u = __builtin_bit_cast(unsigned, f);
    u += 0x7fffu + ((u >> 16) & 1u);
    return (unsigned short)(u >> 16);
}

// DPP row-rotate (within 16-lane rows); CTRL = 0x120 + N for row_ror:N
template <int CTRL>
__device__ __forceinline__ float dppf(float x) {
    int r = __builtin_amdgcn_mov_dpp(__builtin_bit_cast(int, x), CTRL, 0xF, 0xF, false);
    return __builtin_bit_cast(float, r);
}
__device__ __forceinline__ float rowmax16(float v) {
    v = fmaxf(v, dppf<0x121>(v));
    v = fmaxf(v, dppf<0x122>(v));
    v = fmaxf(v, dppf<0x124>(v));
    v = fmaxf(v, dppf<0x128>(v));
    return v;
}
__device__ __forceinline__ float rowsum16(float v) {
    v += dppf<0x121>(v);
    v += dppf<0x122>(v);
    v += dppf<0x124>(v);
    v += dppf<0x128>(v);
    return v;
}

// ---------------------------------------------------------------------------
// K1: fused QKV projection (R1-proven version, verbatim).
// grid (72 n-tiles of 32 cols, 8 k-splits of 256), block 256.
// ---------------------------------------------------------------------------
__launch_bounds__(256)
__global__ void k1_qkv(const float* __restrict__ x,
                       const float* __restrict__ Wq, const float* __restrict__ bq,
                       const float* __restrict__ Wk, const float* __restrict__ bk,
                       const float* __restrict__ Wv, const float* __restrict__ bv,
                       float* __restrict__ qbuf, float* __restrict__ knew,
                       float* __restrict__ vnew) {
    const int tx = threadIdx.x & 31;
    const int ty = threadIdx.x >> 5;   // 0..7
    const int nt = blockIdx.x;         // 0..71
    const int kc = blockIdx.y;         // 0..7
    const int k0 = kc * 256;
    const int col0 = nt * 32;

    const float* W; const float* bias; float* out; int ldW;
    int cbase;
    if (col0 < 2048)       { W = Wq; bias = bq; out = qbuf; ldW = 2048; cbase = col0; }
    else if (col0 < 2176)  { W = Wk; bias = bk; out = knew; ldW = 128;  cbase = col0 - 2048; }
    else                   { W = Wv; bias = bv; out = vnew; ldW = 128;  cbase = col0 - 2176; }
    const int col = cbase + tx;

    __shared__ __align__(16) float xs[64][68];

    float acc[8] = {0, 0, 0, 0, 0, 0, 0, 0};

    for (int sub = 0; sub < 4; ++sub) {
        const int kb = k0 + sub * 64;
        #pragma unroll
        for (int i = 0; i < 4; ++i) {
            int c = threadIdx.x + i * 256;
            int r = c >> 4;
            int cc = (c & 15) << 2;
            float4 v = *(const float4*)(x + (size_t)r * EMBED + kb + cc);
            *(float4*)&xs[r][cc] = v;
        }
        __syncthreads();
        #pragma unroll
        for (int kk = 0; kk < 64; kk += 4) {
            float w0 = W[(size_t)(kb + kk + 0) * ldW + col];
            float w1 = W[(size_t)(kb + kk + 1) * ldW + col];
            float w2 = W[(size_t)(kb + kk + 2) * ldW + col];
            float w3 = W[(size_t)(kb + kk + 3) * ldW + col];
            #pragma unroll
            for (int j = 0; j < 8; ++j) {
                int m = ty + (j << 3);
                float4 xv = *(const float4*)&xs[m][kk];
                acc[j] = fmaf(xv.x, w0, acc[j]);
                acc[j] = fmaf(xv.y, w1, acc[j]);
                acc[j] = fmaf(xv.z, w2, acc[j]);
                acc[j] = fmaf(xv.w, w3, acc[j]);
            }
        }
        __syncthreads();
    }
    if (kc == 0) {
        float b = bias[col];
        #pragma unroll
        for (int j = 0; j < 8; ++j) acc[j] += b;
    }
    const int ldO = (ldW == 2048) ? 2048 : 128;
    #pragma unroll
    for (int j = 0; j < 8; ++j)
        atomicAdd(&out[(size_t)(ty + (j << 3)) * ldO + col], acc[j]);
}

// ---------------------------------------------------------------------------
// K2: flash-decode attention partials (split-KV).
// grid (nch, 64), block 256 (4 waves). Wave owns S_TOT/(nch*4) slots.
// ONLY delta vs R1: K fragments load directly from global (no ksh LDS stage;
// data-identical mapping: slot = s0+lm, d = t*32+quad*8+j), and partial count
// C = nch*4 is grid-derived. Everything else is R1-verbatim.
// ---------------------------------------------------------------------------
__launch_bounds__(256)
__global__ void k2_attn(const float* __restrict__ qbuf,
                        const float* __restrict__ kcache,
                        const float* __restrict__ vcache,
                        const float* __restrict__ knew,
                        const float* __restrict__ vnew,
                        const int* __restrict__ cpos,
                        float* __restrict__ part_o,   // [B][C][16][128]
                        float* __restrict__ part_ml)  // [B][C][16][2]
{
    const int b = blockIdx.y;
    const int chunk = blockIdx.x;
    const int nch = gridDim.x;
    const int C = nch * 4;
    const int spw = S_TOT / C;        // slots per wave (64 or 128)
    const int nst = spw >> 5;         // 32-slot supertiles per wave (2 or 4)
    const int tid = threadIdx.x;
    const int w = tid >> 6;
    const int lane = tid & 63;
    const int quad = lane >> 4;
    const int lm = lane & 15;
    const int pos = cpos[b];

    // LDS 29.9 KB
    __shared__ __align__(16) short qs[16 * 136];       // q bf16 [16][136]
    __shared__ __align__(16) short vsh[4][64 * 40];    // per-wave vT half [64 d][40]
    __shared__ __align__(16) short psh[4][16 * 40];    // per-wave P [16][40]

    // ---- stage q (scaled) as bf16 [16 heads][128 d]
    {
        const int h = tid >> 4, d0 = (tid & 15) << 3;
        const float* src = qbuf + (size_t)b * EMBED + h * HD + d0;
        float4 a = *(const float4*)src;
        float4 c = *(const float4*)(src + 4);
        const float s = 0.08838834764831845f;  // 1/sqrt(128)
        short8v pk;
        pk[0] = f2bf(a.x * s); pk[1] = f2bf(a.y * s);
        pk[2] = f2bf(a.z * s); pk[3] = f2bf(a.w * s);
        pk[4] = f2bf(c.x * s); pk[5] = f2bf(c.y * s);
        pk[6] = f2bf(c.z * s); pk[7] = f2bf(c.w * s);
        *(short8v*)&qs[h * 136 + d0] = pk;
    }
    __syncthreads();

    short8v aq[4];
    #pragma unroll
    for (int t = 0; t < 4; ++t)
        aq[t] = *(short8v*)&qs[lm * 136 + t * 32 + quad * 8];

    short* vt = vsh[w];
    short* pt = psh[w];

    float m_run[4] = {-INFINITY, -INFINITY, -INFINITY, -INFINITY};
    float l_run[4] = {0, 0, 0, 0};
    floatx4 oacc[8];
    #pragma unroll
    for (int i = 0; i < 8; ++i) oacc[i] = (floatx4){0, 0, 0, 0};

    const int sbase = chunk * (S_TOT / nch) + w * spw;

    for (int st = 0; st < nst; ++st) {
        const int st0 = sbase + st * 32;
        floatx4 sc2[2];
        // ---- QK: B-fragments direct from global (slot s0+lm, d=t*32+quad*8+j)
        #pragma unroll
        for (int half = 0; half < 2; ++half) {
            const int s0 = st0 + half * 16;
            const float* krow = kcache + ((size_t)b * S_TOT + s0 + lm) * HD;
            if (lm == pos - s0) krow = knew + (size_t)b * HD;  // new-token subst
            floatx4 s = {0, 0, 0, 0};
            #pragma unroll
            for (int t = 0; t < 4; ++t) {
                float4 ka  = *(const float4*)(krow + t * 32 + quad * 8);
                float4 kb2 = *(const float4*)(krow + t * 32 + quad * 8 + 4);
                short8v bk_;
                bk_[0] = f2bf(ka.x);  bk_[1] = f2bf(ka.y);
                bk_[2] = f2bf(ka.z);  bk_[3] = f2bf(ka.w);
                bk_[4] = f2bf(kb2.x); bk_[5] = f2bf(kb2.y);
                bk_[6] = f2bf(kb2.z); bk_[7] = f2bf(kb2.w);
                s = __builtin_amdgcn_mfma_f32_16x16x32_bf16(aq[t], bk_, s, 0, 0, 0);
            }
            sc2[half] = s;
        }
        // ---- online softmax over the 32 slots (R1 verbatim)
        float alpha[4];
        #pragma unroll
        for (int r = 0; r < 4; ++r) {
            float mt = rowmax16(fmaxf(sc2[0][r], sc2[1][r]));
            float mn = fmaxf(m_run[r], mt);
            alpha[r] = __expf(m_run[r] - mn);
            m_run[r] = mn;
            float pA = __expf(sc2[0][r] - mn);
            float pB = __expf(sc2[1][r] - mn);
            float ss = rowsum16(pA + pB);
            l_run[r] = l_run[r] * alpha[r] + ss;
            pt[(quad * 4 + r) * 40 + lm]      = (short)f2bf(pA);
            pt[(quad * 4 + r) * 40 + 16 + lm] = (short)f2bf(pB);
        }
        #pragma unroll
        for (int dt = 0; dt < 8; ++dt) {
            oacc[dt][0] *= alpha[0]; oacc[dt][1] *= alpha[1];
            oacc[dt][2] *= alpha[2]; oacc[dt][3] *= alpha[3];
        }
        short8v ap = *(short8v*)&pt[lm * 40 + quad * 8];

        // ---- PV in two d-halves (R1 verbatim)
        #pragma unroll
        for (int p = 0; p < 2; ++p) {
            const int sg = lane & 7;     // slot group (4 slots)
            const int dgv = lane >> 3;   // 8 d-groups
            #pragma unroll
            for (int i = 0; i < 2; ++i) {
                int dl = dgv * 4 + i * 32;
                int dglob = p * 64 + dl;
                const float* vb = vcache + ((size_t)b * S_TOT + st0 + sg * 4) * HD + dglob;
                float4 r0 = *(const float4*)(vb + 0 * HD);
                float4 r1 = *(const float4*)(vb + 1 * HD);
                float4 r2 = *(const float4*)(vb + 2 * HD);
                float4 r3 = *(const float4*)(vb + 3 * HD);
                short4v p0, p1, p2, p3;
                p0[0]=f2bf(r0.x); p0[1]=f2bf(r1.x); p0[2]=f2bf(r2.x); p0[3]=f2bf(r3.x);
                p1[0]=f2bf(r0.y); p1[1]=f2bf(r1.y); p1[2]=f2bf(r2.y); p1[3]=f2bf(r3.y);
                p2[0]=f2bf(r0.z); p2[1]=f2bf(r1.z); p2[2]=f2bf(r2.z); p2[3]=f2bf(r3.z);
                p3[0]=f2bf(r0.w); p3[1]=f2bf(r1.w); p3[2]=f2bf(r2.w); p3[3]=f2bf(r3.w);
                *(short4v*)&vt[(dl + 0) * 40 + sg * 4] = p0;
                *(short4v*)&vt[(dl + 1) * 40 + sg * 4] = p1;
                *(short4v*)&vt[(dl + 2) * 40 + sg * 4] = p2;
                *(short4v*)&vt[(dl + 3) * 40 + sg * 4] = p3;
            }
            const int prs = pos - st0;
            if (prs >= 0 && prs < 32) {   // wave-uniform
                float vvn = vnew[b * HD + p * 64 + lane];
                vt[lane * 40 + prs] = (short)f2bf(vvn);
            }
            #pragma unroll
            for (int dq = 0; dq < 4; ++dq) {
                int dt = p * 4 + dq;
                short8v bv_ = *(short8v*)&vt[(dq * 16 + lm) * 40 + quad * 8];
                oacc[dt] = __builtin_amdgcn_mfma_f32_16x16x32_bf16(ap, bv_, oacc[dt], 0, 0, 0);
            }
        }
    }

    // ---- direct per-wave partial write (R1 structure, C partials)
    const int cw = chunk * 4 + w;
    float* po = part_o + (size_t)(b * C + cw) * 16 * 128;
    #pragma unroll
    for (int dt = 0; dt < 8; ++dt)
        #pragma unroll
        for (int r = 0; r < 4; ++r)
            po[(quad * 4 + r) * 128 + dt * 16 + lm] = oacc[dt][r];
    if (lm < 2) {
        #pragma unroll
        for (int r = 0; r < 4; ++r) {
            float v = (lm == 0) ? m_run[r] : l_run[r];
            part_ml[((size_t)(b * C + cw) * 16 + quad * 4 + r) * 2 + lm] = v;
        }
    }
}

// ---------------------------------------------------------------------------
// K3: combine C partials per (b,h) -> attn[b][h*128+d]  (R1 structure + C arg)
// ---------------------------------------------------------------------------
__launch_bounds__(128)
__global__ void k3_combine(const float* __restrict__ part_o,
                           const float* __restrict__ part_ml,
                           float* __restrict__ attn, int C) {
    const int h = blockIdx.x, b = blockIdx.y, d = threadIdx.x;
    __shared__ float sm[64], sl[64];
    if (threadIdx.x < C) {
        sm[threadIdx.x] = part_ml[((size_t)(b * C + threadIdx.x) * 16 + h) * 2 + 0];
        sl[threadIdx.x] = part_ml[((size_t)(b * C + threadIdx.x) * 16 + h) * 2 + 1];
    }
    __syncthreads();
    float M = -INFINITY;
    for (int c = 0; c < C; ++c) M = fmaxf(M, sm[c]);
    float O = 0.f, L = 0.f;
    for (int c = 0; c < C; ++c) {
        float co = __expf(sm[c] - M);
        L += co * sl[c];
        O += co * part_o[((size_t)(b * C + c) * 16 + h) * 128 + d];
    }
    attn[(size_t)b * EMBED + h * HD + d] = O / L;
}

// ---------------------------------------------------------------------------
// K4: output projection (R1-proven version, verbatim). grid (64, 8), block 256.
// ---------------------------------------------------------------------------
__launch_bounds__(256)
__global__ void k4_proj(const float* __restrict__ attn,
                        const float* __restrict__ Wo, const float* __restrict__ bo,
                        float* __restrict__ out) {
    const int tx = threadIdx.x & 31;
    const int ty = threadIdx.x >> 5;
    const int col = blockIdx.x * 32 + tx;
    const int k0 = blockIdx.y * 256;

    __shared__ __align__(16) float xs[64][68];
    float acc[8] = {0, 0, 0, 0, 0, 0, 0, 0};

    for (int sub = 0; sub < 4; ++sub) {
        const int kb = k0 + sub * 64;
        #pragma unroll
        for (int i = 0; i < 4; ++i) {
            int c = threadIdx.x + i * 256;
            int r = c >> 4;
            int cc = (c & 15) << 2;
            float4 v = *(const float4*)(attn + (size_t)r * EMBED + kb + cc);
            *(float4*)&xs[r][cc] = v;
        }
        __syncthreads();
        #pragma unroll
        for (int kk = 0; kk < 64; kk += 4) {
            float w0 = Wo[(size_t)(kb + kk + 0) * EMBED + col];
            float w1 = Wo[(size_t)(kb + kk + 1) * EMBED + col];
            float w2 = Wo[(size_t)(kb + kk + 2) * EMBED + col];
            float w3 = Wo[(size_t)(kb + kk + 3) * EMBED + col];
            #pragma unroll
            for (int j = 0; j < 8; ++j) {
                int m = ty + (j << 3);
                float4 xv = *(const float4*)&xs[m][kk];
                acc[j] = fmaf(xv.x, w0, acc[j]);
                acc[j] = fmaf(xv.y, w1, acc[j]);
                acc[j] = fmaf(xv.z, w2, acc[j]);
                acc[j] = fmaf(xv.w, w3, acc[j]);
            }
        }
        __syncthreads();
    }
    if (blockIdx.y == 0) {
        float b = bo[col];
        #pragma unroll
        for (int j = 0; j < 8; ++j) acc[j] += b;
    }
    #pragma unroll
    for (int j = 0; j < 8; ++j)
        atomicAdd(&out[(size_t)(ty + (j << 3)) * EMBED + col], acc[j]);
}

// ---------------------------------------------------------------------------
extern "C" void kernel_launch(void* const* d_in, const int* in_sizes, int n_in,
                              void* d_out, int out_size, void* d_ws, size_t ws_size,
                              hipStream_t stream) {
    (void)in_sizes; (void)n_in; (void)out_size;
    const float* x  = (const float*)d_in[0];
    const float* kc = (const float*)d_in[1];
    const float* vc = (const float*)d_in[2];
    const int*   cp = (const int*)d_in[3];
    const float* Wq = (const float*)d_in[4];
    const float* bq = (const float*)d_in[5];
    const float* Wk = (const float*)d_in[6];
    const float* bk = (const float*)d_in[7];
    const float* Wv = (const float*)d_in[8];
    const float* bv = (const float*)d_in[9];
    const float* Wo = (const float*)d_in[10];
    const float* bo = (const float*)d_in[11];
    float* out = (float*)d_out;
    float* ws  = (float*)d_ws;

    // ws layout (floats)
    float* qbuf = ws;                    // 131072
    float* knew = ws + 131072;           // 8192
    float* vnew = ws + 139264;           // 8192
    float* attn = ws + 147456;           // 131072
    float* po   = ws + 278528;           // B*C*16*128

    // nch=16 needs 35.2 MB of ws; fall back to R1-proven nch=8 (18.2 MB) if short.
    const size_t need16 = (278528ull + 64ull * 64 * 16 * 128 + 64ull * 64 * 16 * 2) * 4ull;
    const int nch = (ws_size >= need16) ? 16 : 8;
    const int C = nch * 4;
    float* pml = po + (size_t)BATCH * C * 16 * 128;

    hipMemsetAsync(qbuf, 0, 147456 * sizeof(float), stream);   // q/k_new/v_new
    hipMemsetAsync(out, 0, (size_t)BATCH * EMBED * sizeof(float), stream);

    k1_qkv<<<dim3(72, 8), 256, 0, stream>>>(x, Wq, bq, Wk, bk, Wv, bv, qbuf, knew, vnew);
    k2_attn<<<dim3(nch, 64), 256, 0, stream>>>(qbuf, kc, vc, knew, vnew, cp, po, pml);
    k3_combine<<<dim3(16, 64), 128, 0, stream>>>(po, pml, attn, C);
    k4_proj<<<dim3(64, 8), 256, 0, stream>>>(attn, Wo, bo, out);
}

// Round 4
// 395.490 us; speedup vs baseline: 1.0082x; 1.0082x over previous
//
#include <hip/hip_runtime.h>
#include <math.h>

// Problem constants
#define EMBED   2048
#define NHEADS  16
#define HD      128
#define S_TOT   4096
#define BATCH   64
#define NCH     16          // k2 chunks
#define CPART   64          // partials per (b,h) = NCH*4 waves

typedef __attribute__((ext_vector_type(8))) short short8v;
typedef __attribute__((ext_vector_type(4))) short short4v;
typedef __attribute__((ext_vector_type(4))) float floatx4;

// fp32 -> bf16, round-to-nearest-even
__device__ __forceinline__ unsigned short f2bf(float f) {
    unsigned u = __builtin_bit_cast(unsigned, f);
    u += 0x7fffu + ((u >> 16) & 1u);
    return (unsigned short)(u >> 16);
}

// DPP row-rotate (within 16-lane rows); CTRL = 0x120 + N for row_ror:N
template <int CTRL>
__device__ __forceinline__ float dppf(float x) {
    int r = __builtin_amdgcn_mov_dpp(__builtin_bit_cast(int, x), CTRL, 0xF, 0xF, false);
    return __builtin_bit_cast(float, r);
}
__device__ __forceinline__ float rowmax16(float v) {
    v = fmaxf(v, dppf<0x121>(v));
    v = fmaxf(v, dppf<0x122>(v));
    v = fmaxf(v, dppf<0x124>(v));
    v = fmaxf(v, dppf<0x128>(v));
    return v;
}
__device__ __forceinline__ float rowsum16(float v) {
    v += dppf<0x121>(v);
    v += dppf<0x122>(v);
    v += dppf<0x124>(v);
    v += dppf<0x128>(v);
    return v;
}

// ---------------------------------------------------------------------------
// K1: fused QKV projection (R1-proven version, verbatim).
// grid (72 n-tiles of 32 cols, 8 k-splits of 256), block 256.
// ---------------------------------------------------------------------------
__launch_bounds__(256)
__global__ void k1_qkv(const float* __restrict__ x,
                       const float* __restrict__ Wq, const float* __restrict__ bq,
                       const float* __restrict__ Wk, const float* __restrict__ bk,
                       const float* __restrict__ Wv, const float* __restrict__ bv,
                       float* __restrict__ qbuf, float* __restrict__ knew,
                       float* __restrict__ vnew) {
    const int tx = threadIdx.x & 31;
    const int ty = threadIdx.x >> 5;   // 0..7
    const int nt = blockIdx.x;         // 0..71
    const int kc = blockIdx.y;         // 0..7
    const int k0 = kc * 256;
    const int col0 = nt * 32;

    const float* W; const float* bias; float* out; int ldW;
    int cbase;
    if (col0 < 2048)       { W = Wq; bias = bq; out = qbuf; ldW = 2048; cbase = col0; }
    else if (col0 < 2176)  { W = Wk; bias = bk; out = knew; ldW = 128;  cbase = col0 - 2048; }
    else                   { W = Wv; bias = bv; out = vnew; ldW = 128;  cbase = col0 - 2176; }
    const int col = cbase + tx;

    __shared__ __align__(16) float xs[64][68];

    float acc[8] = {0, 0, 0, 0, 0, 0, 0, 0};

    for (int sub = 0; sub < 4; ++sub) {
        const int kb = k0 + sub * 64;
        #pragma unroll
        for (int i = 0; i < 4; ++i) {
            int c = threadIdx.x + i * 256;
            int r = c >> 4;
            int cc = (c & 15) << 2;
            float4 v = *(const float4*)(x + (size_t)r * EMBED + kb + cc);
            *(float4*)&xs[r][cc] = v;
        }
        __syncthreads();
        #pragma unroll
        for (int kk = 0; kk < 64; kk += 4) {
            float w0 = W[(size_t)(kb + kk + 0) * ldW + col];
            float w1 = W[(size_t)(kb + kk + 1) * ldW + col];
            float w2 = W[(size_t)(kb + kk + 2) * ldW + col];
            float w3 = W[(size_t)(kb + kk + 3) * ldW + col];
            #pragma unroll
            for (int j = 0; j < 8; ++j) {
                int m = ty + (j << 3);
                float4 xv = *(const float4*)&xs[m][kk];
                acc[j] = fmaf(xv.x, w0, acc[j]);
                acc[j] = fmaf(xv.y, w1, acc[j]);
                acc[j] = fmaf(xv.z, w2, acc[j]);
                acc[j] = fmaf(xv.w, w3, acc[j]);
            }
        }
        __syncthreads();
    }
    if (kc == 0) {
        float b = bias[col];
        #pragma unroll
        for (int j = 0; j < 8; ++j) acc[j] += b;
    }
    const int ldO = (ldW == 2048) ? 2048 : 128;
    #pragma unroll
    for (int j = 0; j < 8; ++j)
        atomicAdd(&out[(size_t)(ty + (j << 3)) * ldO + col], acc[j]);
}

// ---------------------------------------------------------------------------
// K2: flash-decode attention partials (split-KV).
// grid (16 chunks, 64 batches), block 256 (4 waves). Wave owns 64 slots.
// Deltas vs R3 (proven): V fragments load DIRECTLY from global in B-layout
// (no vsh LDS transpose); V loads issued before softmax to overlap latency.
// K direct-load, softmax, P-through-LDS, partial write: R3-verbatim.
// ---------------------------------------------------------------------------
__launch_bounds__(256)
__global__ void k2_attn(const float* __restrict__ qbuf,
                        const float* __restrict__ kcache,
                        const float* __restrict__ vcache,
                        const float* __restrict__ knew,
                        const float* __restrict__ vnew,
                        const int* __restrict__ cpos,
                        float* __restrict__ part_o,   // [B][64][16][128]
                        float* __restrict__ part_ml)  // [B][64][16][2]
{
    const int b = blockIdx.y;
    const int chunk = blockIdx.x;      // 0..15
    const int tid = threadIdx.x;
    const int w = tid >> 6;
    const int lane = tid & 63;
    const int quad = lane >> 4;
    const int lm = lane & 15;
    const int pos = cpos[b];

    // LDS 9.25 KB
    __shared__ __align__(16) short qs[16 * 136];       // q bf16 [16][136]
    __shared__ __align__(16) short psh[4][16 * 40];    // per-wave P [16][40]

    // ---- stage q (scaled) as bf16 [16 heads][128 d]
    {
        const int h = tid >> 4, d0 = (tid & 15) << 3;
        const float* src = qbuf + (size_t)b * EMBED + h * HD + d0;
        float4 a = *(const float4*)src;
        float4 c = *(const float4*)(src + 4);
        const float s = 0.08838834764831845f;  // 1/sqrt(128)
        short8v pk;
        pk[0] = f2bf(a.x * s); pk[1] = f2bf(a.y * s);
        pk[2] = f2bf(a.z * s); pk[3] = f2bf(a.w * s);
        pk[4] = f2bf(c.x * s); pk[5] = f2bf(c.y * s);
        pk[6] = f2bf(c.z * s); pk[7] = f2bf(c.w * s);
        *(short8v*)&qs[h * 136 + d0] = pk;
    }
    __syncthreads();

    short8v aq[4];
    #pragma unroll
    for (int t = 0; t < 4; ++t)
        aq[t] = *(short8v*)&qs[lm * 136 + t * 32 + quad * 8];

    short* pt = psh[w];

    float m_run[4] = {-INFINITY, -INFINITY, -INFINITY, -INFINITY};
    float l_run[4] = {0, 0, 0, 0};
    floatx4 oacc[8];
    #pragma unroll
    for (int i = 0; i < 8; ++i) oacc[i] = (floatx4){0, 0, 0, 0};

    const int sbase = chunk * 256 + w * 64;

    #pragma unroll
    for (int st = 0; st < 2; ++st) {
        const int st0 = sbase + st * 32;
        floatx4 sc2[2];
        // ---- QK: B-fragments direct from global (R3-proven)
        #pragma unroll
        for (int half = 0; half < 2; ++half) {
            const int s0 = st0 + half * 16;
            const float* krow = kcache + ((size_t)b * S_TOT + s0 + lm) * HD;
            if (lm == pos - s0) krow = knew + (size_t)b * HD;  // new-token subst
            floatx4 s = {0, 0, 0, 0};
            #pragma unroll
            for (int t = 0; t < 4; ++t) {
                float4 ka  = *(const float4*)(krow + t * 32 + quad * 8);
                float4 kb2 = *(const float4*)(krow + t * 32 + quad * 8 + 4);
                short8v bk_;
                bk_[0] = f2bf(ka.x);  bk_[1] = f2bf(ka.y);
                bk_[2] = f2bf(ka.z);  bk_[3] = f2bf(ka.w);
                bk_[4] = f2bf(kb2.x); bk_[5] = f2bf(kb2.y);
                bk_[6] = f2bf(kb2.z); bk_[7] = f2bf(kb2.w);
                s = __builtin_amdgcn_mfma_f32_16x16x32_bf16(aq[t], bk_, s, 0, 0, 0);
            }
            sc2[half] = s;
        }

        // ---- V fragments direct from global in B-layout:
        //      B[n=d=dt*16+lm][k=slot=quad*8+j] = V[st0+quad*8+j][dt*16+lm]
        //      8 dword loads per fragment, shared vaddr, offsets j*512B.
        const int prs = pos - st0;
        short8v bvf[8];
        #pragma unroll
        for (int dt = 0; dt < 8; ++dt) {
            const float* vb = vcache + ((size_t)b * S_TOT + st0 + quad * 8) * HD + dt * 16 + lm;
            float f0 = vb[0 * HD], f1 = vb[1 * HD], f2 = vb[2 * HD], f3 = vb[3 * HD];
            float f4 = vb[4 * HD], f5 = vb[5 * HD], f6 = vb[6 * HD], f7 = vb[7 * HD];
            if (prs >= 0 && prs < 32) {          // wave-uniform, rarely taken
                float vn = vnew[b * HD + dt * 16 + lm];
                int jb = prs - quad * 8;         // per-lane predicates
                if (jb == 0) f0 = vn; if (jb == 1) f1 = vn;
                if (jb == 2) f2 = vn; if (jb == 3) f3 = vn;
                if (jb == 4) f4 = vn; if (jb == 5) f5 = vn;
                if (jb == 6) f6 = vn; if (jb == 7) f7 = vn;
            }
            short8v t;
            t[0] = f2bf(f0); t[1] = f2bf(f1); t[2] = f2bf(f2); t[3] = f2bf(f3);
            t[4] = f2bf(f4); t[5] = f2bf(f5); t[6] = f2bf(f6); t[7] = f2bf(f7);
            bvf[dt] = t;
        }

        // ---- online softmax over the 32 slots (R3 verbatim)
        float alpha[4];
        #pragma unroll
        for (int r = 0; r < 4; ++r) {
            float mt = rowmax16(fmaxf(sc2[0][r], sc2[1][r]));
            float mn = fmaxf(m_run[r], mt);
            alpha[r] = __expf(m_run[r] - mn);
            m_run[r] = mn;
            float pA = __expf(sc2[0][r] - mn);
            float pB = __expf(sc2[1][r] - mn);
            float ss = rowsum16(pA + pB);
            l_run[r] = l_run[r] * alpha[r] + ss;
            pt[(quad * 4 + r) * 40 + lm]      = (short)f2bf(pA);
            pt[(quad * 4 + r) * 40 + 16 + lm] = (short)f2bf(pB);
        }
        #pragma unroll
        for (int dt = 0; dt < 8; ++dt) {
            oacc[dt][0] *= alpha[0]; oacc[dt][1] *= alpha[1];
            oacc[dt][2] *= alpha[2]; oacc[dt][3] *= alpha[3];
        }
        short8v ap = *(short8v*)&pt[lm * 40 + quad * 8];

        // ---- PV from register fragments
        #pragma unroll
        for (int dt = 0; dt < 8; ++dt)
            oacc[dt] = __builtin_amdgcn_mfma_f32_16x16x32_bf16(ap, bvf[dt], oacc[dt], 0, 0, 0);
    }

    // ---- per-wave partial write (R3 verbatim, C=64)
    const int cw = chunk * 4 + w;
    float* po = part_o + (size_t)(b * CPART + cw) * 16 * 128;
    #pragma unroll
    for (int dt = 0; dt < 8; ++dt)
        #pragma unroll
        for (int r = 0; r < 4; ++r)
            po[(quad * 4 + r) * 128 + dt * 16 + lm] = oacc[dt][r];
    if (lm < 2) {
        #pragma unroll
        for (int r = 0; r < 4; ++r) {
            float v = (lm == 0) ? m_run[r] : l_run[r];
            part_ml[((size_t)(b * CPART + cw) * 16 + quad * 4 + r) * 2 + lm] = v;
        }
    }
}

// ---------------------------------------------------------------------------
// K3: combine 64 partials per (b,h) -> attn[b][h*128+d].
// Compile-time C, exp once in LDS, 8 independent accumulators.
// ---------------------------------------------------------------------------
__launch_bounds__(128)
__global__ void k3_combine(const float* __restrict__ part_o,
                           const float* __restrict__ part_ml,
                           float* __restrict__ attn) {
    const int h = blockIdx.x, b = blockIdx.y, d = threadIdx.x;
    __shared__ float sm[CPART], sl[CPART], sco[CPART];
    if (d < CPART) {
        sm[d] = part_ml[((size_t)(b * CPART + d) * 16 + h) * 2 + 0];
        sl[d] = part_ml[((size_t)(b * CPART + d) * 16 + h) * 2 + 1];
    }
    __syncthreads();
    float M = -INFINITY;
    #pragma unroll
    for (int c = 0; c < CPART; ++c) M = fmaxf(M, sm[c]);
    if (d < CPART) sco[d] = __expf(sm[d] - M);
    __syncthreads();
    float L = 0.f;
    #pragma unroll
    for (int c = 0; c < CPART; ++c) L += sco[c] * sl[c];
    float O[8] = {0, 0, 0, 0, 0, 0, 0, 0};
    #pragma unroll
    for (int cc = 0; cc < CPART; cc += 8) {
        #pragma unroll
        for (int u = 0; u < 8; ++u)
            O[u] = fmaf(sco[cc + u],
                        part_o[((size_t)(b * CPART + cc + u) * 16 + h) * 128 + d],
                        O[u]);
    }
    float Os = ((O[0] + O[1]) + (O[2] + O[3])) + ((O[4] + O[5]) + (O[6] + O[7]));
    attn[(size_t)b * EMBED + h * HD + d] = Os / L;
}

// ---------------------------------------------------------------------------
// K4: output projection (R1-proven version, verbatim). grid (64, 8), block 256.
// ---------------------------------------------------------------------------
__launch_bounds__(256)
__global__ void k4_proj(const float* __restrict__ attn,
                        const float* __restrict__ Wo, const float* __restrict__ bo,
                        float* __restrict__ out) {
    const int tx = threadIdx.x & 31;
    const int ty = threadIdx.x >> 5;
    const int col = blockIdx.x * 32 + tx;
    const int k0 = blockIdx.y * 256;

    __shared__ __align__(16) float xs[64][68];
    float acc[8] = {0, 0, 0, 0, 0, 0, 0, 0};

    for (int sub = 0; sub < 4; ++sub) {
        const int kb = k0 + sub * 64;
        #pragma unroll
        for (int i = 0; i < 4; ++i) {
            int c = threadIdx.x + i * 256;
            int r = c >> 4;
            int cc = (c & 15) << 2;
            float4 v = *(const float4*)(attn + (size_t)r * EMBED + kb + cc);
            *(float4*)&xs[r][cc] = v;
        }
        __syncthreads();
        #pragma unroll
        for (int kk = 0; kk < 64; kk += 4) {
            float w0 = Wo[(size_t)(kb + kk + 0) * EMBED + col];
            float w1 = Wo[(size_t)(kb + kk + 1) * EMBED + col];
            float w2 = Wo[(size_t)(kb + kk + 2) * EMBED + col];
            float w3 = Wo[(size_t)(kb + kk + 3) * EMBED + col];
            #pragma unroll
            for (int j = 0; j < 8; ++j) {
                int m = ty + (j << 3);
                float4 xv = *(const float4*)&xs[m][kk];
                acc[j] = fmaf(xv.x, w0, acc[j]);
                acc[j] = fmaf(xv.y, w1, acc[j]);
                acc[j] = fmaf(xv.z, w2, acc[j]);
                acc[j] = fmaf(xv.w, w3, acc[j]);
            }
        }
        __syncthreads();
    }
    if (blockIdx.y == 0) {
        float b = bo[col];
        #pragma unroll
        for (int j = 0; j < 8; ++j) acc[j] += b;
    }
    #pragma unroll
    for (int j = 0; j < 8; ++j)
        atomicAdd(&out[(size_t)(ty + (j << 3)) * EMBED + col], acc[j]);
}

// ---------------------------------------------------------------------------
extern "C" void kernel_launch(void* const* d_in, const int* in_sizes, int n_in,
                              void* d_out, int out_size, void* d_ws, size_t ws_size,
                              hipStream_t stream) {
    (void)in_sizes; (void)n_in; (void)out_size; (void)ws_size;
    const float* x  = (const float*)d_in[0];
    const float* kc = (const float*)d_in[1];
    const float* vc = (const float*)d_in[2];
    const int*   cp = (const int*)d_in[3];
    const float* Wq = (const float*)d_in[4];
    const float* bq = (const float*)d_in[5];
    const float* bk = (const float*)d_in[7];
    const float* Wk = (const float*)d_in[6];
    const float* Wv = (const float*)d_in[8];
    const float* bv = (const float*)d_in[9];
    const float* Wo = (const float*)d_in[10];
    const float* bo = (const float*)d_in[11];
    float* out = (float*)d_out;
    float* ws  = (float*)d_ws;

    // ws layout (floats); C=64 path needs 35.2 MB (proven present in R3)
    float* qbuf = ws;                    // 131072
    float* knew = ws + 131072;           // 8192
    float* vnew = ws + 139264;           // 8192
    float* attn = ws + 147456;           // 131072
    float* po   = ws + 278528;           // 64*64*16*128 = 8388608
    float* pml  = po + (size_t)BATCH * CPART * 16 * 128;   // 64*64*16*2

    hipMemsetAsync(qbuf, 0, 147456 * sizeof(float), stream);   // q/k_new/v_new
    hipMemsetAsync(out, 0, (size_t)BATCH * EMBED * sizeof(float), stream);

    k1_qkv<<<dim3(72, 8), 256, 0, stream>>>(x, Wq, bq, Wk, bk, Wv, bv, qbuf, knew, vnew);
    k2_attn<<<dim3(NCH, 64), 256, 0, stream>>>(qbuf, kc, vc, knew, vnew, cp, po, pml);
    k3_combine<<<dim3(16, 64), 128, 0, stream>>>(po, pml, attn);
    k4_proj<<<dim3(64, 8), 256, 0, stream>>>(attn, Wo, bo, out);
}